// Round 5
// baseline (46509.900 us; speedup 1.0000x reference)
//
#include <hip/hip_runtime.h>
#include <stdint.h>

// DiffusionModel R9 = R8 + last two source-level VALU cuts (fp-contract is
// off everywhere, so the compiler can't make these itself):
//  1. Accumulate folded into the poly output: v = med3(fma(x, p, v)) replaces
//     (mul; add; med3). Single vs double rounding: <=0.5 ulp/step ~6e-8,
//     random-walk < 2e-6 over 1000 clipped steps. Reverse: fma(-x, p, v),
//     negate is a free VOP3 input modifier. Saves 1 VALU/elem.
//  2. #pragma unroll 2 on the t loop: amortizes ds_read + 2x readfirstlane +
//     k2/k01 SALU + loop branch (~6-8 slots/iter). Body 2x~350 inst ~ 5.6 KB,
//     fits 32 KB L1I.
// R8 post-mortem: add3 injection fusion was already emitted (no delta); tail
// boundary move gave its ~3%. Duration tracks emitted VALU cycles 1:1 at a
// structural ~60% issue efficiency. Modeled practical floor ~43.5 ms; if R9
// gains <2% we are at the issue roofline.
// Audited & rejected: branchless tail (always-sqrt + 6 cndmask > 4.7% branch
// cost), single wide poly in w or sqrt(w) (Chebyshev rate => 14-21 terms),
// cvt of full b (NaN hazard at b ~ 2^32: RN(b)*2^-31 can exceed 1), packed
// int threefry (no v_pk_add_u32 on CDNA), v_xad_u32 (xor-then-add, we need
// add-then-xor).

#define NTOTAL 25165824u
#define EPT    4u
#define NTHREADS (NTOTAL / EPT)   // 6,291,456 threads = 24576 blocks x 256
#define TS     1000

// c = 0.1*sqrt2, host-folded in float exactly as R4 did.
#define KC (0.1f * 1.41421356f)

__device__ __forceinline__ uint32_t rotl32(uint32_t x, int r) {
  // alignbit(a,b,c) = (a:b) >> c  =>  alignbit(x,x,32-r) = rotl(x,r)
  return __builtin_amdgcn_alignbit(x, x, 32 - r);
}

// Full 20-round threefry2x32 for key derivation (preludes only).
__device__ __forceinline__ void tf2x32(uint32_t k0, uint32_t k1,
                                       uint32_t x0, uint32_t x1,
                                       uint32_t& o0, uint32_t& o1) {
  const uint32_t k2 = k0 ^ k1 ^ 0x1BD11BDAu;
  x0 += k0; x1 += k1;
#define RR(r) { x0 += x1; x1 = rotl32(x1, r); x1 ^= x0; }
  RR(13) RR(15) RR(26) RR(6)
  x0 += k1; x1 += k2 + 1u;
  RR(17) RR(29) RR(16) RR(24)
  x0 += k2; x1 += k0 + 2u;
  RR(13) RR(15) RR(26) RR(6)
  x0 += k0; x1 += k1 + 3u;
  RR(17) RR(29) RR(16) RR(24)
  x0 += k1; x1 += k2 + 4u;
  RR(13) RR(15) RR(26) RR(6)
  x0 += k2; x1 += k0 + 5u;
#undef RR
  o0 = x0; o1 = x1;
}

// Hot-loop threefry: counter (0, i), XOR-fold. Injection+round fused
// (v_add3_u32 pattern, 1 SGPR operand); uniform (kX+c) on SALU. Bit-exact
// (mod-2^32 associativity).
__device__ __forceinline__ uint32_t tf_bits(uint32_t k0, uint32_t k1,
                                            uint32_t k2, uint32_t k01,
                                            uint32_t i) {
#define RN(r) { x0 += x1; x1 = rotl32(x1, r); x1 ^= x0; }
#define RF(kA, kBc, r) { x1 += (kBc); x0 = x0 + (kA) + x1; \
                         x1 = rotl32(x1, r); x1 ^= x0; }
  uint32_t x1 = i + k1;        // injected x1
  uint32_t x0 = i + k01;       // == k0 + x1, k01 = k0+k1 on SALU
  x1 = rotl32(x1, 13); x1 ^= x0;
  RN(15) RN(26) RN(6)
  RF(k1, k2 + 1u, 17) RN(29) RN(16) RN(24)
  RF(k2, k0 + 2u, 13) RN(15) RN(26) RN(6)
  RF(k0, k1 + 3u, 17) RN(29) RN(16) RN(24)
  RF(k1, k2 + 4u, 13) RN(15) RN(26) RN(6)
  return (x0 + k2) ^ (x1 + (k0 + 5u));
#undef RN
#undef RF
}

__device__ __forceinline__ float clamp01(float v) {
  return __builtin_amdgcn_fmed3f(v, 0.0f, 1.0f);  // == min(1,max(0,v)) finite
}

// p(b) = c * erfinv-poly, x(b) = uniform in (-1,1); noise = x*p.
// Identical math to R8's noise_from_bits, but returns (x, p) so the caller
// can fold the accumulate into one fma.
__device__ __forceinline__ void xp_from_bits(uint32_t b, float& x, float& p) {
#pragma clang fp contract(off)
  float mf = (float)(b >> 9);              // v_cvt_f32_u32, exact (< 2^24)
  x = fmaf(mf, 0x1p-22f, -0.99999994f);
  float t = x * x;
  float u = 1.0f - t;      // two roundings, ref-identical; do NOT fma
  float L = __log2f(u);    // raw v_log_f32; u normal
  // s = w - 2.5 where w = -ln(u): fused, <=1 ulp vs (mul, neg-sub)
  float s = fmaf(L, -0x1.62e43p-1f, -2.5f);
  if (__builtin_expect(!(s < 4.0f), 0)) {  // w >= 6.5, P ~ 0.075%/draw
    float s3 = sqrtf(s + 2.5f) - 3.0f;     // sqrt(w) - 3 (+-2ulp arg, benign)
    p = KC * -0.00367342844f;
    p = fmaf(p, s3, KC * 0.00573950773f);
    p = fmaf(p, s3, KC * -0.0076224613f);
    p = fmaf(p, s3, KC * 0.00943887047f);
    p = fmaf(p, s3, KC * 1.00167406f);
    p = fmaf(p, s3, KC * 2.83297682f);
  } else {
    p = KC * -4.39150654e-06f;
    p = fmaf(p, s, KC * 0.00021858087f);
    p = fmaf(p, s, KC * -0.00125372503f);
    p = fmaf(p, s, KC * -0.00417768164f);
    p = fmaf(p, s, KC * 0.246640727f);
    p = fmaf(p, s, KC * 1.50140941f);
  }
}

// forward step: v <- clip(v + x*p). fma-folded (deviation <= 0.5 ulp/step).
__device__ __forceinline__ float fwd_step(uint32_t b, float v) {
#pragma clang fp contract(off)
  float x, p;
  xp_from_bits(b, x, p);
  return clamp01(fmaf(x, p, v));
}

// reverse step: v <- clip(v - x*p). -x is a free input modifier.
__device__ __forceinline__ float rev_step(uint32_t b, float v) {
#pragma clang fp contract(off)
  float x, p;
  xp_from_bits(b, x, p);
  return clamp01(fmaf(-x, p, v));
}

__global__ __launch_bounds__(256) void diffusion_kernel(
    const float* __restrict__ x, float* __restrict__ out) {
  // Step keys (partitionable split): key_t = threefry((0,1), (0,t)).
  // +1 pad slot so the t+1 prefetch never reads OOB.
  __shared__ alignas(16) uint2 skeys[TS + 1];
  const int tid = threadIdx.x;
  for (int j = tid; j < TS + 1; j += 256) {
    uint32_t o0, o1;
    tf2x32(0u, 1u, 0u, (uint32_t)(j < TS ? j : 0), o0, o1);
    skeys[j] = make_uint2(o0, o1);
  }
  __syncthreads();

  const uint32_t i = blockIdx.x * 256u + (uint32_t)tid;  // exact grid
  const uint32_t base = i * EPT;

  float4 xv = ((const float4*)x)[i];
  float v[EPT] = {xv.x, xv.y, xv.z, xv.w};

  uint2 kcur = skeys[0];
#pragma unroll 2
  for (int t = 0; t < TS; ++t) {
    const uint32_t k0 = (uint32_t)__builtin_amdgcn_readfirstlane((int)kcur.x);
    const uint32_t k1 = (uint32_t)__builtin_amdgcn_readfirstlane((int)kcur.y);
    kcur = skeys[t + 1];  // prefetch next key; waitcnt lands far from use
    const uint32_t k2  = k0 ^ k1 ^ 0x1BD11BDAu;  // uniform -> SALU
    const uint32_t k01 = k0 + k1;                // uniform -> SALU
    uint32_t b[EPT];
#pragma unroll
    for (uint32_t e = 0; e < EPT; ++e) b[e] = tf_bits(k0, k1, k2, k01, base + e);
#pragma unroll
    for (uint32_t e = 0; e < EPT; ++e) v[e] = fwd_step(b[e], v[e]);
  }

  // rev_key = fold_in(key(2), 999) = threefry((0,2),(0,999)) — constant-folded.
  uint32_t rk0, rk1;
  tf2x32(0u, 2u, 0u, 999u, rk0, rk1);
  const uint32_t rk2  = rk0 ^ rk1 ^ 0x1BD11BDAu;
  const uint32_t rk01 = rk0 + rk1;
  float4 ov;
  float* op = &ov.x;
#pragma unroll
  for (uint32_t e = 0; e < EPT; ++e) {
    op[e] = rev_step(tf_bits(rk0, rk1, rk2, rk01, base + e), v[e]);
  }
  ((float4*)out)[i] = ov;
}

extern "C" void kernel_launch(void* const* d_in, const int* in_sizes, int n_in,
                              void* d_out, int out_size, void* d_ws, size_t ws_size,
                              hipStream_t stream) {
  (void)in_sizes; (void)n_in; (void)d_ws; (void)ws_size; (void)out_size;
  const float* x = (const float*)d_in[0];
  float* out = (float*)d_out;
  dim3 block(256);
  dim3 grid(NTHREADS / 256);  // 24576 blocks
  hipLaunchKernelGGL(diffusion_kernel, grid, block, 0, stream, x, out);
}

// Round 6
// 45325.748 us; speedup vs baseline: 1.0261x; 1.0261x over previous
//
#include <hip/hip_runtime.h>
#include <stdint.h>

// DiffusionModel R10 = R9 minus the unroll-2 (keep the fma-folded step).
// R9 post-mortem: #pragma unroll 2 made the dispatch population BIMODAL —
// slow dispatches showed FETCH_SIZE 49 -> 107-109 MB (+58 MB of pure
// instruction re-fetch; data traffic is fixed) and 65-78 ms duration. The
// doubled loop body thrashes L1I under 32-wave/CU contention. Reverted.
// Kept from R9 (sound, was masked): accumulate folded into one fma —
// v = med3(fma(x, p, v)) / med3(fma(-x, p, v)); single-vs-double rounding
// <= 0.5 ulp/step, random-walk < 2e-6 over 1000 clipped steps. -1 VALU/elem.
// R8 recap: VALU-issue-bound (HBM 0.04%, MFMA 0, LDS-conflict 0); duration
// tracks emitted VALU cycles 1:1 at ~60% structural issue efficiency.
// Modeled practical floor ~43.5 ms dispatch; R8 = 44.6-45.0. If R10 is
// neutral-or-worse vs R8, we are at the issue roofline.

#define NTOTAL 25165824u
#define EPT    4u
#define NTHREADS (NTOTAL / EPT)   // 6,291,456 threads = 24576 blocks x 256
#define TS     1000

// c = 0.1*sqrt2, host-folded in float exactly as R4 did.
#define KC (0.1f * 1.41421356f)

__device__ __forceinline__ uint32_t rotl32(uint32_t x, int r) {
  // alignbit(a,b,c) = (a:b) >> c  =>  alignbit(x,x,32-r) = rotl(x,r)
  return __builtin_amdgcn_alignbit(x, x, 32 - r);
}

// Full 20-round threefry2x32 for key derivation (preludes only).
__device__ __forceinline__ void tf2x32(uint32_t k0, uint32_t k1,
                                       uint32_t x0, uint32_t x1,
                                       uint32_t& o0, uint32_t& o1) {
  const uint32_t k2 = k0 ^ k1 ^ 0x1BD11BDAu;
  x0 += k0; x1 += k1;
#define RR(r) { x0 += x1; x1 = rotl32(x1, r); x1 ^= x0; }
  RR(13) RR(15) RR(26) RR(6)
  x0 += k1; x1 += k2 + 1u;
  RR(17) RR(29) RR(16) RR(24)
  x0 += k2; x1 += k0 + 2u;
  RR(13) RR(15) RR(26) RR(6)
  x0 += k0; x1 += k1 + 3u;
  RR(17) RR(29) RR(16) RR(24)
  x0 += k1; x1 += k2 + 4u;
  RR(13) RR(15) RR(26) RR(6)
  x0 += k2; x1 += k0 + 5u;
#undef RR
  o0 = x0; o1 = x1;
}

// Hot-loop threefry: counter (0, i), XOR-fold. Injection+round fused
// (v_add3_u32 pattern, 1 SGPR operand); uniform (kX+c) on SALU. Bit-exact
// (mod-2^32 associativity).
__device__ __forceinline__ uint32_t tf_bits(uint32_t k0, uint32_t k1,
                                            uint32_t k2, uint32_t k01,
                                            uint32_t i) {
#define RN(r) { x0 += x1; x1 = rotl32(x1, r); x1 ^= x0; }
#define RF(kA, kBc, r) { x1 += (kBc); x0 = x0 + (kA) + x1; \
                         x1 = rotl32(x1, r); x1 ^= x0; }
  uint32_t x1 = i + k1;        // injected x1
  uint32_t x0 = i + k01;       // == k0 + x1, k01 = k0+k1 on SALU
  x1 = rotl32(x1, 13); x1 ^= x0;
  RN(15) RN(26) RN(6)
  RF(k1, k2 + 1u, 17) RN(29) RN(16) RN(24)
  RF(k2, k0 + 2u, 13) RN(15) RN(26) RN(6)
  RF(k0, k1 + 3u, 17) RN(29) RN(16) RN(24)
  RF(k1, k2 + 4u, 13) RN(15) RN(26) RN(6)
  return (x0 + k2) ^ (x1 + (k0 + 5u));
#undef RN
#undef RF
}

__device__ __forceinline__ float clamp01(float v) {
  return __builtin_amdgcn_fmed3f(v, 0.0f, 1.0f);  // == min(1,max(0,v)) finite
}

// p(b) = c * erfinv-poly, x(b) = uniform in (-1,1); noise = x*p.
// Returns (x, p) so the caller folds the accumulate into one fma.
__device__ __forceinline__ void xp_from_bits(uint32_t b, float& x, float& p) {
#pragma clang fp contract(off)
  float mf = (float)(b >> 9);              // v_cvt_f32_u32, exact (< 2^24)
  x = fmaf(mf, 0x1p-22f, -0.99999994f);
  float t = x * x;
  float u = 1.0f - t;      // two roundings, ref-identical; do NOT fma
  float L = __log2f(u);    // raw v_log_f32; u normal
  // s = w - 2.5 where w = -ln(u): fused, <=1 ulp vs (mul, neg-sub)
  float s = fmaf(L, -0x1.62e43p-1f, -2.5f);
  if (__builtin_expect(!(s < 4.0f), 0)) {  // w >= 6.5, P ~ 0.075%/draw
    float s3 = sqrtf(s + 2.5f) - 3.0f;     // sqrt(w) - 3 (+-2ulp arg, benign)
    p = KC * -0.00367342844f;
    p = fmaf(p, s3, KC * 0.00573950773f);
    p = fmaf(p, s3, KC * -0.0076224613f);
    p = fmaf(p, s3, KC * 0.00943887047f);
    p = fmaf(p, s3, KC * 1.00167406f);
    p = fmaf(p, s3, KC * 2.83297682f);
  } else {
    p = KC * -4.39150654e-06f;
    p = fmaf(p, s, KC * 0.00021858087f);
    p = fmaf(p, s, KC * -0.00125372503f);
    p = fmaf(p, s, KC * -0.00417768164f);
    p = fmaf(p, s, KC * 0.246640727f);
    p = fmaf(p, s, KC * 1.50140941f);
  }
}

// forward step: v <- clip(v + x*p). fma-folded (deviation <= 0.5 ulp/step).
__device__ __forceinline__ float fwd_step(uint32_t b, float v) {
#pragma clang fp contract(off)
  float x, p;
  xp_from_bits(b, x, p);
  return clamp01(fmaf(x, p, v));
}

// reverse step: v <- clip(v - x*p). -x is a free input modifier.
__device__ __forceinline__ float rev_step(uint32_t b, float v) {
#pragma clang fp contract(off)
  float x, p;
  xp_from_bits(b, x, p);
  return clamp01(fmaf(-x, p, v));
}

__global__ __launch_bounds__(256) void diffusion_kernel(
    const float* __restrict__ x, float* __restrict__ out) {
  // Step keys (partitionable split): key_t = threefry((0,1), (0,t)).
  // +1 pad slot so the t+1 prefetch never reads OOB.
  __shared__ alignas(16) uint2 skeys[TS + 1];
  const int tid = threadIdx.x;
  for (int j = tid; j < TS + 1; j += 256) {
    uint32_t o0, o1;
    tf2x32(0u, 1u, 0u, (uint32_t)(j < TS ? j : 0), o0, o1);
    skeys[j] = make_uint2(o0, o1);
  }
  __syncthreads();

  const uint32_t i = blockIdx.x * 256u + (uint32_t)tid;  // exact grid
  const uint32_t base = i * EPT;

  float4 xv = ((const float4*)x)[i];
  float v[EPT] = {xv.x, xv.y, xv.z, xv.w};

  uint2 kcur = skeys[0];
  for (int t = 0; t < TS; ++t) {
    const uint32_t k0 = (uint32_t)__builtin_amdgcn_readfirstlane((int)kcur.x);
    const uint32_t k1 = (uint32_t)__builtin_amdgcn_readfirstlane((int)kcur.y);
    kcur = skeys[t + 1];  // prefetch next key; waitcnt lands far from use
    const uint32_t k2  = k0 ^ k1 ^ 0x1BD11BDAu;  // uniform -> SALU
    const uint32_t k01 = k0 + k1;                // uniform -> SALU
    uint32_t b[EPT];
#pragma unroll
    for (uint32_t e = 0; e < EPT; ++e) b[e] = tf_bits(k0, k1, k2, k01, base + e);
#pragma unroll
    for (uint32_t e = 0; e < EPT; ++e) v[e] = fwd_step(b[e], v[e]);
  }

  // rev_key = fold_in(key(2), 999) = threefry((0,2),(0,999)) — constant-folded.
  uint32_t rk0, rk1;
  tf2x32(0u, 2u, 0u, 999u, rk0, rk1);
  const uint32_t rk2  = rk0 ^ rk1 ^ 0x1BD11BDAu;
  const uint32_t rk01 = rk0 + rk1;
  float4 ov;
  float* op = &ov.x;
#pragma unroll
  for (uint32_t e = 0; e < EPT; ++e) {
    op[e] = rev_step(tf_bits(rk0, rk1, rk2, rk01, base + e), v[e]);
  }
  ((float4*)out)[i] = ov;
}

extern "C" void kernel_launch(void* const* d_in, const int* in_sizes, int n_in,
                              void* d_out, int out_size, void* d_ws, size_t ws_size,
                              hipStream_t stream) {
  (void)in_sizes; (void)n_in; (void)d_ws; (void)ws_size; (void)out_size;
  const float* x = (const float*)d_in[0];
  float* out = (float*)d_out;
  dim3 block(256);
  dim3 grid(NTHREADS / 256);  // 24576 blocks
  hipLaunchKernelGGL(diffusion_kernel, grid, block, 0, stream, x, out);
}